// Round 2
// baseline (1565.917 us; speedup 1.0000x reference)
//
#include <hip/hip_runtime.h>
#include <hip/hip_bf16.h>

// Meta3D block: LN1 -> QKV -> MFMA-attn(+rel-pos bias) -> proj(+ls1 resid)
//               LN2 -> FC1+GELU -> FC2(+ls2 resid)
// B=1024 imgs, N=49 tok, C=448. GEMMs are y = x @ W.T (NT), bf16 MFMA 16x16x32.
// R4: GEMM tile 128x128 -> 256x256 (8 waves, 512 thr). The R3 kernel was
// staging-throughput bound (~14 B/cyc/CU delivered, 64 FLOP/staged-byte -> ~500 TF);
// doubling the tile doubles FLOP per staged byte (128 FLOP/B). Same 2-phase
// dbuf global_load_lds structure (prefetch distance 1, one barrier/iter).
// (R4 resubmit: previous round failed with GPUAcquisitionTimeout, no data.)

#define NTOK 49
#define CDIM 448
#define NHEAD 8
#define DHID 1024
#define HQKV 1536
#define FHID 1792
#define QK_SCALE 0.1767766952966369f
#define INV_SCALE 5.656854249492381f

typedef __attribute__((ext_vector_type(8))) short bf16x8;
typedef __attribute__((ext_vector_type(4))) float f32x4;
typedef unsigned int u32;

__device__ __forceinline__ short f2b(float f) {
    __hip_bfloat16 h = __float2bfloat16(f);
    return *reinterpret_cast<short*>(&h);
}

// async global->LDS, 16B per lane; LDS dest = wave-uniform base + lane*16
__device__ __forceinline__ void gll16(const short* g, short* l) {
    __builtin_amdgcn_global_load_lds(
        (const __attribute__((address_space(1))) u32*)g,
        (__attribute__((address_space(3))) u32*)l, 16, 0, 0);
}

// ---------------- weight fp32 -> bf16 (once per launch) ----------------
__global__ __launch_bounds__(256) void convert_w(
    const float* __restrict__ s0, const float* __restrict__ s1,
    const float* __restrict__ s2, const float* __restrict__ s3,
    short* __restrict__ d0, short* __restrict__ d1,
    short* __restrict__ d2, short* __restrict__ d3)
{
    int i = blockIdx.x * 256 + threadIdx.x;
    if (i < 688128) d0[i] = f2b(s0[i]);        // qkv_w 1536x448
    if (i < 458752) d1[i] = f2b(s1[i]);        // proj_w 448x1024
    if (i < 802816) { d2[i] = f2b(s2[i]);      // fc1_w 1792x448
                      d3[i] = f2b(s3[i]); }    // fc2_w 448x1792
}

// ---------------- expand rel-pos bias to full [8,49,49] fp32 ----------------
__global__ __launch_bounds__(256) void build_bias(
    const float* __restrict__ biases, const int* __restrict__ bidx,
    float* __restrict__ bfull)
{
    int i = blockIdx.x * 256 + threadIdx.x;
    if (i < NHEAD * NTOK * NTOK) {
        int h = i / (NTOK * NTOK), p = i % (NTOK * NTOK);
        bfull[i] = biases[h * NTOK + bidx[p]];
    }
}

// ---------------- LayerNorm: fp32 -> bf16, one wave per 448-row ----------------
__global__ __launch_bounds__(256) void ln_kernel(
    const float* __restrict__ x, short* __restrict__ out,
    const float* __restrict__ g, const float* __restrict__ b)
{
    int row = blockIdx.x * 4 + (threadIdx.x >> 6);
    int lane = threadIdx.x & 63;
    const float* xr = x + (size_t)row * CDIM;
    float v[7];
    float s = 0.f;
#pragma unroll
    for (int i = 0; i < 7; i++) { v[i] = xr[i * 64 + lane]; s += v[i]; }
#pragma unroll
    for (int o = 32; o > 0; o >>= 1) s += __shfl_xor(s, o, 64);
    float mean = s * (1.0f / 448.0f);
    float q = 0.f;
#pragma unroll
    for (int i = 0; i < 7; i++) { float d = v[i] - mean; q += d * d; }
#pragma unroll
    for (int o = 32; o > 0; o >>= 1) q += __shfl_xor(q, o, 64);
    float rstd = rsqrtf(q * (1.0f / 448.0f) + 1e-5f);
    short* orow = out + (size_t)row * CDIM;
#pragma unroll
    for (int i = 0; i < 7; i++) {
        int c = i * 64 + lane;
        orow[c] = f2b((v[i] - mean) * rstd * g[c] + b[c]);
    }
}

// ---------------- bf16 NT GEMM, 256x256 tile, BK=32, dbuf global_load_lds ----------------
// 8 waves. LDS per matrix per buf: 16 panels of (16 rows x 32 k), panel k-quad-major
// so the DMA dest and frag reads are both base + lane*16 (conflict-free).
// Wave w stages panels {2w,2w+1} of A and of B. Wave output tile: 128x64
// (wm=(w&1)*128, wn=(w>>1)*64) -> acc[8][4] f32x4.
// Pipeline: iter i computes buf i&1; the top-of-iter barrier drains only DMAs
// issued a full iteration earlier -> drain is cheap.
// EPI 0: out_bf16 = acc + bias[col]
// EPI 1: out_bf16 = gelu_exact(acc + bias[col])
// EPI 2: out_f32  = resid[row,col] + (acc + bias[col]) * ls[col]
template <int EPI>
__global__ __launch_bounds__(512, 2) void gemm_bt(
    const short* __restrict__ A,     // [M,K] bf16 (rows clamped if M%256)
    const short* __restrict__ W,     // [N,K] bf16 (rows clamped if N%256)
    const float* __restrict__ bias,  // [N]
    const float* __restrict__ ls,    // [N]   (EPI 2)
    const float* __restrict__ resid, // [M,N] (EPI 2)
    float* __restrict__ outF,        // (EPI 2)
    short* __restrict__ outB,        // (EPI 0/1)
    int M, int N, int K)
{
    __shared__ short sA[2][8192];   // 2 x 16KB
    __shared__ short sB[2][8192];
    const int tid = threadIdx.x;
    const int lane = tid & 63;
    const int w = tid >> 6;          // 0..7
    const int lr = lane & 15, lq = lane >> 4;
    const int m0 = blockIdx.y * 256;
    const int n0 = blockIdx.x * 256;

    // wave w stages panels {2w, 2w+1}; within a panel: row = lr, k-offset = lq*8
    const int p0 = 2 * w, p1 = 2 * w + 1;
    int rA0 = m0 + p0 * 16 + lr; rA0 = rA0 < M ? rA0 : M - 1;
    int rA1 = m0 + p1 * 16 + lr; rA1 = rA1 < M ? rA1 : M - 1;
    int rB0 = n0 + p0 * 16 + lr; rB0 = rB0 < N ? rB0 : N - 1;
    int rB1 = n0 + p1 * 16 + lr; rB1 = rB1 < N ? rB1 : N - 1;
    const short* pA0 = A + (size_t)rA0 * K + lq * 8;
    const short* pA1 = A + (size_t)rA1 * K + lq * 8;
    const short* pB0 = W + (size_t)rB0 * K + lq * 8;
    const short* pB1 = W + (size_t)rB1 * K + lq * 8;
    const int oA0 = p0 * 512, oA1 = p1 * 512;   // panel offsets in shorts

    const f32x4 fz = {0.f, 0.f, 0.f, 0.f};
    f32x4 acc[8][4];
#pragma unroll
    for (int i = 0; i < 8; i++)
#pragma unroll
        for (int j = 0; j < 4; j++) acc[i][j] = fz;

    const int rdA = (w & 1) * 8192 + lane * 16;   // byte offset inside buffer
    const int rdB = (w >> 1) * 4096 + lane * 16;

    // prologue: stage tile 0 into buf 0
    gll16(pA0, sA[0] + oA0); gll16(pA1, sA[0] + oA1);
    gll16(pB0, sB[0] + oA0); gll16(pB1, sB[0] + oA1);
    pA0 += 32; pA1 += 32; pB0 += 32; pB1 += 32;

    int buf = 0;
    for (int k0 = 0; k0 < K; k0 += 32) {
        __syncthreads();          // drains DMAs issued one iteration ago
        if (k0 + 32 < K) {        // prefetch next tile into other buffer
            short* dA = sA[buf ^ 1];
            short* dB = sB[buf ^ 1];
            gll16(pA0, dA + oA0); gll16(pA1, dA + oA1);
            gll16(pB0, dB + oA0); gll16(pB1, dB + oA1);
            pA0 += 32; pA1 += 32; pB0 += 32; pB1 += 32;
        }
        const char* baseA = (const char*)sA[buf] + rdA;
        const char* baseB = (const char*)sB[buf] + rdB;
        bf16x8 af[8], bfb[4];
#pragma unroll
        for (int i = 0; i < 8; i++) af[i] = *(const bf16x8*)(baseA + i * 1024);
#pragma unroll
        for (int j = 0; j < 4; j++) bfb[j] = *(const bf16x8*)(baseB + j * 1024);
#pragma unroll
        for (int i = 0; i < 8; i++)
#pragma unroll
            for (int j = 0; j < 4; j++)
                acc[i][j] = __builtin_amdgcn_mfma_f32_16x16x32_bf16(
                    af[i], bfb[j], acc[i][j], 0, 0, 0);
        buf ^= 1;
    }

    const int wm = (w & 1) * 128, wn = (w >> 1) * 64;
    // C/D layout: col=lane&15, row=(lane>>4)*4+reg  [verified m89/m91]
#pragma unroll
    for (int i = 0; i < 8; i++)
#pragma unroll
        for (int j = 0; j < 4; j++)
#pragma unroll
            for (int r = 0; r < 4; r++) {
                int row = m0 + wm + i * 16 + lq * 4 + r;
                int col = n0 + wn + j * 16 + lr;
                if (row < M && col < N) {
                    float v = acc[i][j][r] + bias[col];
                    if (EPI == 0) {
                        outB[(size_t)row * N + col] = f2b(v);
                    } else if (EPI == 1) {
                        float gl = 0.5f * v * (1.0f + erff(v * 0.7071067811865475f));
                        outB[(size_t)row * N + col] = f2b(gl);
                    } else {
                        outF[(size_t)row * N + col] =
                            resid[(size_t)row * N + col] + v * ls[col];
                    }
                }
            }
}

// ---------------- MFMA attention: 1 wave per (image, head) ----------------
__global__ __launch_bounds__(64) void attn_mfma(
    const short* __restrict__ qkv,    // [R,1536]; per-head 192 = q32|k32|v128
    const float* __restrict__ bfull,  // [8,49,49] fp32
    short* __restrict__ attn_out)     // [R,1024]
{
    __shared__ short sP[64 * 72];     // P bf16, row stride 144B (16B aligned)
    __shared__ short sVt[128 * 72];   // V^T bf16 [d][tok(0..63)]
    const int head = blockIdx.x;
    const size_t base = (size_t)blockIdx.y * NTOK;
    const int lane = threadIdx.x;
    const int lr = lane & 15, lq = lane >> 4;

    // C-init = bias/SCALE; mask cols>=49 with -1e30 (survives MFMA add + *SCALE)
    f32x4 sc[4][4];
#pragma unroll
    for (int i = 0; i < 4; i++)
#pragma unroll
        for (int j = 0; j < 4; j++)
#pragma unroll
            for (int r = 0; r < 4; r++) {
                int row = i * 16 + lq * 4 + r, col = j * 16 + lr;
                float v;
                if (col >= NTOK)      v = -1e30f;
                else if (row < NTOK)  v = bfull[head * (NTOK * NTOK) + row * NTOK + col] * INV_SCALE;
                else                  v = 0.f;
                sc[i][j][r] = v;
            }

    // Q/K fragments straight from global (k-contiguous 16B; rows clamped)
    bf16x8 qf[4], kf[4];
#pragma unroll
    for (int i = 0; i < 4; i++) {
        int r = i * 16 + lr; r = r < NTOK ? r : NTOK - 1;
        const short* rp = qkv + (base + r) * HQKV + head * 192;
        qf[i] = *(const bf16x8*)(rp + lq * 8);
        kf[i] = *(const bf16x8*)(rp + 32 + lq * 8);
    }
#pragma unroll
    for (int i = 0; i < 4; i++)
#pragma unroll
        for (int j = 0; j < 4; j++)
            sc[i][j] = __builtin_amdgcn_mfma_f32_16x16x32_bf16(
                qf[i], kf[j], sc[i][j], 0, 0, 0);

    // stage V^T: [d][tok], zero-pad toks 49..63 (P there is exactly 0)
    for (int e = lane; e < NTOK * 128; e += 64) {
        int tok = e >> 7, d = e & 127;
        sVt[d * 72 + tok] = qkv[(base + tok) * HQKV + head * 192 + 64 + d];
    }
    for (int t = lane; t < 128 * 15; t += 64) {
        int d = t / 15, tok = NTOK + t % 15;
        sVt[d * 72 + tok] = 0;
    }

    // softmax over (j regs x 16 lanes) per output row; P -> sP as bf16
#pragma unroll
    for (int i = 0; i < 4; i++)
#pragma unroll
        for (int r = 0; r < 4; r++) {
            float s0 = sc[i][0][r] * QK_SCALE;
            float s1 = sc[i][1][r] * QK_SCALE;
            float s2 = sc[i][2][r] * QK_SCALE;
            float s3 = sc[i][3][r] * QK_SCALE;
            float m = fmaxf(fmaxf(s0, s1), fmaxf(s2, s3));
#pragma unroll
            for (int o = 1; o < 16; o <<= 1) m = fmaxf(m, __shfl_xor(m, o, 64));
            float e0 = __expf(s0 - m), e1 = __expf(s1 - m);
            float e2 = __expf(s2 - m), e3 = __expf(s3 - m);
            float l = e0 + e1 + e2 + e3;
#pragma unroll
            for (int o = 1; o < 16; o <<= 1) l += __shfl_xor(l, o, 64);
            float inv = 1.0f / l;
            short* pr = &sP[(i * 16 + lq * 4 + r) * 72];
            pr[lr]      = f2b(e0 * inv);
            pr[16 + lr] = f2b(e1 * inv);
            pr[32 + lr] = f2b(e2 * inv);
            pr[48 + lr] = f2b(e3 * inv);
        }
    __syncthreads();

    // PV: A = P (rows=query, k=token), B = V^T rows (n=d, k=token); 2 d-halves
    bf16x8 pa[4][2];
#pragma unroll
    for (int i = 0; i < 4; i++)
#pragma unroll
        for (int kk = 0; kk < 2; kk++)
            pa[i][kk] = *(const bf16x8*)&sP[(i * 16 + lr) * 72 + kk * 32 + lq * 8];

#pragma unroll
    for (int half = 0; half < 2; half++) {
        const f32x4 fz = {0.f, 0.f, 0.f, 0.f};
        f32x4 o[4][4];
        bf16x8 pb[4][2];
#pragma unroll
        for (int j = 0; j < 4; j++)
#pragma unroll
            for (int kk = 0; kk < 2; kk++)
                pb[j][kk] = *(const bf16x8*)
                    &sVt[(half * 64 + j * 16 + lr) * 72 + kk * 32 + lq * 8];
#pragma unroll
        for (int i = 0; i < 4; i++)
#pragma unroll
            for (int j = 0; j < 4; j++) {
                o[i][j] = __builtin_amdgcn_mfma_f32_16x16x32_bf16(
                    pa[i][0], pb[j][0], fz, 0, 0, 0);
                o[i][j] = __builtin_amdgcn_mfma_f32_16x16x32_bf16(
                    pa[i][1], pb[j][1], o[i][j], 0, 0, 0);
            }
#pragma unroll
        for (int i = 0; i < 4; i++)
#pragma unroll
            for (int j = 0; j < 4; j++)
#pragma unroll
                for (int r = 0; r < 4; r++) {
                    int row = i * 16 + lq * 4 + r;
                    if (row < NTOK)
                        attn_out[(base + row) * DHID + head * 128 + half * 64 + j * 16 + lr] =
                            f2b(o[i][j][r]);
                }
    }
}

extern "C" void kernel_launch(void* const* d_in, const int* in_sizes, int n_in,
                              void* d_out, int out_size, void* d_ws, size_t ws_size,
                              hipStream_t stream) {
    const float* x      = (const float*)d_in[0];
    const float* qkv_w  = (const float*)d_in[1];
    const float* qkv_b  = (const float*)d_in[2];
    const float* proj_w = (const float*)d_in[3];
    const float* proj_b = (const float*)d_in[4];
    const float* fc1_w  = (const float*)d_in[5];
    const float* fc1_b  = (const float*)d_in[6];
    const float* fc2_w  = (const float*)d_in[7];
    const float* fc2_b  = (const float*)d_in[8];
    const float* n1g    = (const float*)d_in[9];
    const float* n1b    = (const float*)d_in[10];
    const float* n2g    = (const float*)d_in[11];
    const float* n2b    = (const float*)d_in[12];
    const float* ls1    = (const float*)d_in[13];
    const float* ls2    = (const float*)d_in[14];
    const float* biases = (const float*)d_in[15];
    const int*   bidx   = (const int*)d_in[16];
    float* outp = (float*)d_out;

    char* ws = (char*)d_ws;
    short* Wq = (short*)ws; ws += (size_t)688128 * 2;
    short* Wp = (short*)ws; ws += (size_t)458752 * 2;
    short* W1 = (short*)ws; ws += (size_t)802816 * 2;
    short* W2 = (short*)ws; ws += (size_t)802816 * 2;
    float* bfull = (float*)ws; ws += (size_t)NHEAD * NTOK * NTOK * 4;
    const size_t fixed = 5505024 + (size_t)NHEAD * NTOK * NTOK * 4;

    int IC = 1024;
    while (IC > 128) {
        size_t Rr = (size_t)IC * NTOK;
        if (fixed + Rr * 7808ull <= ws_size) break;
        IC >>= 1;
    }
    const size_t R = (size_t)IC * NTOK;
    short* hbuf = (short*)ws; ws += R * CDIM * 2;   // LN out (reused LN2)
    float* x1   = (float*)ws; ws += R * CDIM * 4;   // post-attn residual fp32
    short* qkvb = (short*)ws; ws += R * HQKV * 2;
    short* attb = (short*)ws; ws += R * DHID * 2;
    short* gbuf = qkvb;  // FC1 out [R,1792] overlays qkv+attn (dead by then)

    convert_w<<<3136, 256, 0, stream>>>(qkv_w, proj_w, fc1_w, fc2_w, Wq, Wp, W1, W2);
    build_bias<<<(NHEAD * NTOK * NTOK + 255) / 256, 256, 0, stream>>>(biases, bidx, bfull);

    for (int c0 = 0; c0 < 1024; c0 += IC) {
        const float* xc = x + (size_t)c0 * NTOK * CDIM;
        float* oc = outp + (size_t)c0 * NTOK * CDIM;
        const int Ri = IC * NTOK;
        const int gy = (Ri + 255) / 256;

        ln_kernel<<<Ri / 4, 256, 0, stream>>>(xc, hbuf, n1g, n1b);
        gemm_bt<0><<<dim3(HQKV / 256, gy), 512, 0, stream>>>(
            hbuf, Wq, qkv_b, nullptr, nullptr, nullptr, qkvb, Ri, HQKV, CDIM);
        attn_mfma<<<dim3(NHEAD, IC), 64, 0, stream>>>(qkvb, bfull, attb);
        gemm_bt<2><<<dim3(2, gy), 512, 0, stream>>>(
            attb, Wp, proj_b, ls1, xc, x1, nullptr, Ri, CDIM, DHID);
        ln_kernel<<<Ri / 4, 256, 0, stream>>>(x1, hbuf, n2g, n2b);
        gemm_bt<1><<<dim3(FHID / 256, gy), 512, 0, stream>>>(
            hbuf, W1, fc1_b, nullptr, nullptr, nullptr, gbuf, Ri, FHID, CDIM);
        gemm_bt<2><<<dim3(2, gy), 512, 0, stream>>>(
            gbuf, W2, fc2_b, ls2, x1, oc, nullptr, Ri, CDIM, FHID);
    }
}

// Round 3
// 1354.672 us; speedup vs baseline: 1.1559x; 1.1559x over previous
//
#include <hip/hip_runtime.h>
#include <hip/hip_bf16.h>

// Meta3D block: LN1 -> QKV -> MFMA-attn(+rel-pos bias) -> proj(+ls1 resid)
//               LN2 -> FC1+GELU -> FC2(+ls2 resid)
// B=1024 imgs, N=49 tok, C=448. GEMMs are y = x @ W.T (NT), bf16 MFMA 16x16x32.
// R5: GEMM back to 128x128/4-wave (R4's 256x256 regressed: fewer blocks/CU ->
// less TLP for a latency-bound loop). The real bottleneck is the vmcnt(0) drain
// at __syncthreads each K-step (DMAs get only ~1 short iter to land). Fix =
// T3+T4: 3-buffer ring, prefetch distance 2, counted s_waitcnt vmcnt(4) + raw
// s_barrier -- never drain to 0 in the main loop. LDS 48KB -> 3 blocks/CU.

#define NTOK 49
#define CDIM 448
#define NHEAD 8
#define DHID 1024
#define HQKV 1536
#define FHID 1792
#define QK_SCALE 0.1767766952966369f
#define INV_SCALE 5.656854249492381f

typedef __attribute__((ext_vector_type(8))) short bf16x8;
typedef __attribute__((ext_vector_type(4))) float f32x4;
typedef unsigned int u32;

__device__ __forceinline__ short f2b(float f) {
    __hip_bfloat16 h = __float2bfloat16(f);
    return *reinterpret_cast<short*>(&h);
}

// async global->LDS, 16B per lane; LDS dest = wave-uniform base + lane*16
__device__ __forceinline__ void gll16(const short* g, short* l) {
    __builtin_amdgcn_global_load_lds(
        (const __attribute__((address_space(1))) u32*)g,
        (__attribute__((address_space(3))) u32*)l, 16, 0, 0);
}

// ---------------- weight fp32 -> bf16 (once per launch) ----------------
__global__ __launch_bounds__(256) void convert_w(
    const float* __restrict__ s0, const float* __restrict__ s1,
    const float* __restrict__ s2, const float* __restrict__ s3,
    short* __restrict__ d0, short* __restrict__ d1,
    short* __restrict__ d2, short* __restrict__ d3)
{
    int i = blockIdx.x * 256 + threadIdx.x;
    if (i < 688128) d0[i] = f2b(s0[i]);        // qkv_w 1536x448
    if (i < 458752) d1[i] = f2b(s1[i]);        // proj_w 448x1024
    if (i < 802816) { d2[i] = f2b(s2[i]);      // fc1_w 1792x448
                      d3[i] = f2b(s3[i]); }    // fc2_w 448x1792
}

// ---------------- expand rel-pos bias to full [8,49,49] fp32 ----------------
__global__ __launch_bounds__(256) void build_bias(
    const float* __restrict__ biases, const int* __restrict__ bidx,
    float* __restrict__ bfull)
{
    int i = blockIdx.x * 256 + threadIdx.x;
    if (i < NHEAD * NTOK * NTOK) {
        int h = i / (NTOK * NTOK), p = i % (NTOK * NTOK);
        bfull[i] = biases[h * NTOK + bidx[p]];
    }
}

// ---------------- LayerNorm: fp32 -> bf16, one wave per 448-row ----------------
__global__ __launch_bounds__(256) void ln_kernel(
    const float* __restrict__ x, short* __restrict__ out,
    const float* __restrict__ g, const float* __restrict__ b)
{
    int row = blockIdx.x * 4 + (threadIdx.x >> 6);
    int lane = threadIdx.x & 63;
    const float* xr = x + (size_t)row * CDIM;
    float v[7];
    float s = 0.f;
#pragma unroll
    for (int i = 0; i < 7; i++) { v[i] = xr[i * 64 + lane]; s += v[i]; }
#pragma unroll
    for (int o = 32; o > 0; o >>= 1) s += __shfl_xor(s, o, 64);
    float mean = s * (1.0f / 448.0f);
    float q = 0.f;
#pragma unroll
    for (int i = 0; i < 7; i++) { float d = v[i] - mean; q += d * d; }
#pragma unroll
    for (int o = 32; o > 0; o >>= 1) q += __shfl_xor(q, o, 64);
    float rstd = rsqrtf(q * (1.0f / 448.0f) + 1e-5f);
    short* orow = out + (size_t)row * CDIM;
#pragma unroll
    for (int i = 0; i < 7; i++) {
        int c = i * 64 + lane;
        orow[c] = f2b((v[i] - mean) * rstd * g[c] + b[c]);
    }
}

// ---------------- bf16 NT GEMM, 128x128 tile, BK=32, 3-deep DMA ring ----------------
// 4 waves. LDS per buffer per matrix: 8 panels of (16 rows x 32 k), panel
// k-quad-major -> DMA dest and frag reads are both base + lane*16 (no conflicts).
// Ring schedule (distance 2, 3 buffers): at iter t the wave waits vmcnt(4)
// (its 4 tile-t DMAs done; tile-(t+1)'s 4 stay IN FLIGHT across the barrier),
// crosses a raw s_barrier (no implicit vmcnt(0) drain -- that drain was the
// whole bottleneck), then issues tile t+2 into buffer (t+2)%3. Safe because
// buffer (t+2)%3 is neither the compute buffer t%3 nor the in-flight (t+1)%3,
// and all reads of its previous occupant (tile t-1) finished before the barrier.
// EPI 0: out_bf16 = acc + bias[col]
// EPI 1: out_bf16 = gelu_exact(acc + bias[col])
// EPI 2: out_f32  = resid[row,col] + (acc + bias[col]) * ls[col]
template <int EPI>
__global__ __launch_bounds__(256, 3) void gemm_bt(
    const short* __restrict__ A,     // [M,K] bf16 (M % 128 == 0)
    const short* __restrict__ W,     // [N,K] bf16 (rows clamped if N%128)
    const float* __restrict__ bias,  // [N]
    const float* __restrict__ ls,    // [N]   (EPI 2)
    const float* __restrict__ resid, // [M,N] (EPI 2)
    float* __restrict__ outF,        // (EPI 2)
    short* __restrict__ outB,        // (EPI 0/1)
    int M, int N, int K)
{
    __shared__ short sA[3][4096];   // 3 x 8KB
    __shared__ short sB[3][4096];
    const int tid = threadIdx.x;
    const int lane = tid & 63;
    const int w = tid >> 6;
    const int lr = lane & 15, lq = lane >> 4;
    const int m0 = blockIdx.y * 128;
    const int n0 = blockIdx.x * 128;

    // wave w stages panels {2w, 2w+1}; lane chunk: row = lr, k-offset = lq*8
    const int it0 = 2 * w, it1 = 2 * w + 1;
    const short* pA0 = A + (size_t)(m0 + it0 * 16 + lr) * K + lq * 8;
    const short* pA1 = A + (size_t)(m0 + it1 * 16 + lr) * K + lq * 8;
    int rB0 = n0 + it0 * 16 + lr; rB0 = rB0 < N ? rB0 : N - 1;
    int rB1 = n0 + it1 * 16 + lr; rB1 = rB1 < N ? rB1 : N - 1;
    const short* pB0 = W + (size_t)rB0 * K + lq * 8;
    const short* pB1 = W + (size_t)rB1 * K + lq * 8;
    const int oA0 = it0 * 512, oA1 = it1 * 512;   // panel offsets (shorts)

    const f32x4 fz = {0.f, 0.f, 0.f, 0.f};
    f32x4 acc[4][4];
#pragma unroll
    for (int i = 0; i < 4; i++)
#pragma unroll
        for (int j = 0; j < 4; j++) acc[i][j] = fz;

    const int rdA = (w & 1) * 4096 + lane * 16;   // byte offset inside buffer
    const int rdB = (w >> 1) * 4096 + lane * 16;

    const int nt = K >> 5;   // always >= 14 here
    // prologue: stage tiles 0 and 1
    gll16(pA0, sA[0] + oA0); gll16(pA1, sA[0] + oA1);
    gll16(pB0, sB[0] + oA0); gll16(pB1, sB[0] + oA1);
    pA0 += 32; pA1 += 32; pB0 += 32; pB1 += 32;
    gll16(pA0, sA[1] + oA0); gll16(pA1, sA[1] + oA1);
    gll16(pB0, sB[1] + oA0); gll16(pB1, sB[1] + oA1);
    pA0 += 32; pA1 += 32; pB0 += 32; pB1 += 32;

    int bc = 0;   // compute buffer
    int bs = 2;   // stage buffer
    for (int t = 0; t < nt; t++) {
        // tile t's DMAs done; tile t+1's 4 stay in flight across the barrier
        if (t + 1 < nt) asm volatile("s_waitcnt vmcnt(4)" ::: "memory");
        else            asm volatile("s_waitcnt vmcnt(0)" ::: "memory");
        __builtin_amdgcn_s_barrier();
        if (t + 2 < nt) {
            short* dA = sA[bs];
            short* dB = sB[bs];
            gll16(pA0, dA + oA0); gll16(pA1, dA + oA1);
            gll16(pB0, dB + oA0); gll16(pB1, dB + oA1);
            pA0 += 32; pA1 += 32; pB0 += 32; pB1 += 32;
            bs = (bs == 2) ? 0 : bs + 1;
        }
        const char* baseA = (const char*)sA[bc] + rdA;
        const char* baseB = (const char*)sB[bc] + rdB;
        bc = (bc == 2) ? 0 : bc + 1;
        bf16x8 af[4], bfb[4];
#pragma unroll
        for (int i = 0; i < 4; i++) af[i] = *(const bf16x8*)(baseA + i * 1024);
#pragma unroll
        for (int j = 0; j < 4; j++) bfb[j] = *(const bf16x8*)(baseB + j * 1024);
#pragma unroll
        for (int i = 0; i < 4; i++)
#pragma unroll
            for (int j = 0; j < 4; j++)
                acc[i][j] = __builtin_amdgcn_mfma_f32_16x16x32_bf16(
                    af[i], bfb[j], acc[i][j], 0, 0, 0);
    }

    const int wm = (w & 1) * 64, wn = (w >> 1) * 64;
    // C/D layout: col=lane&15, row=(lane>>4)*4+reg  [verified m89/m91]
#pragma unroll
    for (int i = 0; i < 4; i++)
#pragma unroll
        for (int j = 0; j < 4; j++)
#pragma unroll
            for (int r = 0; r < 4; r++) {
                int row = m0 + wm + i * 16 + lq * 4 + r;
                int col = n0 + wn + j * 16 + lr;
                if (col < N) {
                    float v = acc[i][j][r] + bias[col];
                    if (EPI == 0) {
                        outB[(size_t)row * N + col] = f2b(v);
                    } else if (EPI == 1) {
                        float gl = 0.5f * v * (1.0f + erff(v * 0.7071067811865475f));
                        outB[(size_t)row * N + col] = f2b(gl);
                    } else {
                        outF[(size_t)row * N + col] =
                            resid[(size_t)row * N + col] + v * ls[col];
                    }
                }
            }
}

// ---------------- MFMA attention: 1 wave per (image, head) ----------------
__global__ __launch_bounds__(64) void attn_mfma(
    const short* __restrict__ qkv,    // [R,1536]; per-head 192 = q32|k32|v128
    const float* __restrict__ bfull,  // [8,49,49] fp32
    short* __restrict__ attn_out)     // [R,1024]
{
    __shared__ short sP[64 * 72];     // P bf16, row stride 144B (16B aligned)
    __shared__ short sVt[128 * 72];   // V^T bf16 [d][tok(0..63)]
    const int head = blockIdx.x;
    const size_t base = (size_t)blockIdx.y * NTOK;
    const int lane = threadIdx.x;
    const int lr = lane & 15, lq = lane >> 4;

    // C-init = bias/SCALE; mask cols>=49 with -1e30 (survives MFMA add + *SCALE)
    f32x4 sc[4][4];
#pragma unroll
    for (int i = 0; i < 4; i++)
#pragma unroll
        for (int j = 0; j < 4; j++)
#pragma unroll
            for (int r = 0; r < 4; r++) {
                int row = i * 16 + lq * 4 + r, col = j * 16 + lr;
                float v;
                if (col >= NTOK)      v = -1e30f;
                else if (row < NTOK)  v = bfull[head * (NTOK * NTOK) + row * NTOK + col] * INV_SCALE;
                else                  v = 0.f;
                sc[i][j][r] = v;
            }

    // Q/K fragments straight from global (k-contiguous 16B; rows clamped)
    bf16x8 qf[4], kf[4];
#pragma unroll
    for (int i = 0; i < 4; i++) {
        int r = i * 16 + lr; r = r < NTOK ? r : NTOK - 1;
        const short* rp = qkv + (base + r) * HQKV + head * 192;
        qf[i] = *(const bf16x8*)(rp + lq * 8);
        kf[i] = *(const bf16x8*)(rp + 32 + lq * 8);
    }
#pragma unroll
    for (int i = 0; i < 4; i++)
#pragma unroll
        for (int j = 0; j < 4; j++)
            sc[i][j] = __builtin_amdgcn_mfma_f32_16x16x32_bf16(
                qf[i], kf[j], sc[i][j], 0, 0, 0);

    // stage V^T: [d][tok], zero-pad toks 49..63 (P there is exactly 0)
    for (int e = lane; e < NTOK * 128; e += 64) {
        int tok = e >> 7, d = e & 127;
        sVt[d * 72 + tok] = qkv[(base + tok) * HQKV + head * 192 + 64 + d];
    }
    for (int t = lane; t < 128 * 15; t += 64) {
        int d = t / 15, tok = NTOK + t % 15;
        sVt[d * 72 + tok] = 0;
    }

    // softmax over (j regs x 16 lanes) per output row; P -> sP as bf16
#pragma unroll
    for (int i = 0; i < 4; i++)
#pragma unroll
        for (int r = 0; r < 4; r++) {
            float s0 = sc[i][0][r] * QK_SCALE;
            float s1 = sc[i][1][r] * QK_SCALE;
            float s2 = sc[i][2][r] * QK_SCALE;
            float s3 = sc[i][3][r] * QK_SCALE;
            float m = fmaxf(fmaxf(s0, s1), fmaxf(s2, s3));
#pragma unroll
            for (int o = 1; o < 16; o <<= 1) m = fmaxf(m, __shfl_xor(m, o, 64));
            float e0 = __expf(s0 - m), e1 = __expf(s1 - m);
            float e2 = __expf(s2 - m), e3 = __expf(s3 - m);
            float l = e0 + e1 + e2 + e3;
#pragma unroll
            for (int o = 1; o < 16; o <<= 1) l += __shfl_xor(l, o, 64);
            float inv = 1.0f / l;
            short* pr = &sP[(i * 16 + lq * 4 + r) * 72];
            pr[lr]      = f2b(e0 * inv);
            pr[16 + lr] = f2b(e1 * inv);
            pr[32 + lr] = f2b(e2 * inv);
            pr[48 + lr] = f2b(e3 * inv);
        }
    __syncthreads();

    // PV: A = P (rows=query, k=token), B = V^T rows (n=d, k=token); 2 d-halves
    bf16x8 pa[4][2];
#pragma unroll
    for (int i = 0; i < 4; i++)
#pragma unroll
        for (int kk = 0; kk < 2; kk++)
            pa[i][kk] = *(const bf16x8*)&sP[(i * 16 + lr) * 72 + kk * 32 + lq * 8];

#pragma unroll
    for (int half = 0; half < 2; half++) {
        const f32x4 fz = {0.f, 0.f, 0.f, 0.f};
        f32x4 o[4][4];
        bf16x8 pb[4][2];
#pragma unroll
        for (int j = 0; j < 4; j++)
#pragma unroll
            for (int kk = 0; kk < 2; kk++)
                pb[j][kk] = *(const bf16x8*)
                    &sVt[(half * 64 + j * 16 + lr) * 72 + kk * 32 + lq * 8];
#pragma unroll
        for (int i = 0; i < 4; i++)
#pragma unroll
            for (int j = 0; j < 4; j++) {
                o[i][j] = __builtin_amdgcn_mfma_f32_16x16x32_bf16(
                    pa[i][0], pb[j][0], fz, 0, 0, 0);
                o[i][j] = __builtin_amdgcn_mfma_f32_16x16x32_bf16(
                    pa[i][1], pb[j][1], o[i][j], 0, 0, 0);
            }
#pragma unroll
        for (int i = 0; i < 4; i++)
#pragma unroll
            for (int j = 0; j < 4; j++)
#pragma unroll
                for (int r = 0; r < 4; r++) {
                    int row = i * 16 + lq * 4 + r;
                    if (row < NTOK)
                        attn_out[(base + row) * DHID + head * 128 + half * 64 + j * 16 + lr] =
                            f2b(o[i][j][r]);
                }
    }
}

extern "C" void kernel_launch(void* const* d_in, const int* in_sizes, int n_in,
                              void* d_out, int out_size, void* d_ws, size_t ws_size,
                              hipStream_t stream) {
    const float* x      = (const float*)d_in[0];
    const float* qkv_w  = (const float*)d_in[1];
    const float* qkv_b  = (const float*)d_in[2];
    const float* proj_w = (const float*)d_in[3];
    const float* proj_b = (const float*)d_in[4];
    const float* fc1_w  = (const float*)d_in[5];
    const float* fc1_b  = (const float*)d_in[6];
    const float* fc2_w  = (const float*)d_in[7];
    const float* fc2_b  = (const float*)d_in[8];
    const float* n1g    = (const float*)d_in[9];
    const float* n1b    = (const float*)d_in[10];
    const float* n2g    = (const float*)d_in[11];
    const float* n2b    = (const float*)d_in[12];
    const float* ls1    = (const float*)d_in[13];
    const float* ls2    = (const float*)d_in[14];
    const float* biases = (const float*)d_in[15];
    const int*   bidx   = (const int*)d_in[16];
    float* outp = (float*)d_out;

    char* ws = (char*)d_ws;
    short* Wq = (short*)ws; ws += (size_t)688128 * 2;
    short* Wp = (short*)ws; ws += (size_t)458752 * 2;
    short* W1 = (short*)ws; ws += (size_t)802816 * 2;
    short* W2 = (short*)ws; ws += (size_t)802816 * 2;
    float* bfull = (float*)ws; ws += (size_t)NHEAD * NTOK * NTOK * 4;
    const size_t fixed = 5505024 + (size_t)NHEAD * NTOK * NTOK * 4;

    int IC = 1024;
    while (IC > 128) {
        size_t Rr = (size_t)IC * NTOK;
        if (fixed + Rr * 7808ull <= ws_size) break;
        IC >>= 1;
    }
    const size_t R = (size_t)IC * NTOK;
    short* hbuf = (short*)ws; ws += R * CDIM * 2;   // LN out (reused LN2)
    float* x1   = (float*)ws; ws += R * CDIM * 4;   // post-attn residual fp32
    short* qkvb = (short*)ws; ws += R * HQKV * 2;
    short* attb = (short*)ws; ws += R * DHID * 2;
    short* gbuf = qkvb;  // FC1 out [R,1792] overlays qkv+attn (dead by then)

    convert_w<<<3136, 256, 0, stream>>>(qkv_w, proj_w, fc1_w, fc2_w, Wq, Wp, W1, W2);
    build_bias<<<(NHEAD * NTOK * NTOK + 255) / 256, 256, 0, stream>>>(biases, bidx, bfull);

    for (int c0 = 0; c0 < 1024; c0 += IC) {
        const float* xc = x + (size_t)c0 * NTOK * CDIM;
        float* oc = outp + (size_t)c0 * NTOK * CDIM;
        const int Ri = IC * NTOK;

        ln_kernel<<<Ri / 4, 256, 0, stream>>>(xc, hbuf, n1g, n1b);
        gemm_bt<0><<<dim3(HQKV / 128, Ri / 128), 256, 0, stream>>>(
            hbuf, Wq, qkv_b, nullptr, nullptr, nullptr, qkvb, Ri, HQKV, CDIM);
        attn_mfma<<<dim3(NHEAD, IC), 64, 0, stream>>>(qkvb, bfull, attb);
        gemm_bt<2><<<dim3(4, Ri / 128), 256, 0, stream>>>(
            attb, Wp, proj_b, ls1, xc, x1, nullptr, Ri, CDIM, DHID);
        ln_kernel<<<Ri / 4, 256, 0, stream>>>(x1, hbuf, n2g, n2b);
        gemm_bt<1><<<dim3(FHID / 128, Ri / 128), 256, 0, stream>>>(
            hbuf, W1, fc1_b, nullptr, nullptr, nullptr, gbuf, Ri, FHID, CDIM);
        gemm_bt<2><<<dim3(4, Ri / 128), 256, 0, stream>>>(
            gbuf, W2, fc2_b, ls2, x1, oc, nullptr, Ri, CDIM, FHID);
    }
}

// Round 4
// 1187.663 us; speedup vs baseline: 1.3185x; 1.1406x over previous
//
#include <hip/hip_runtime.h>
#include <hip/hip_bf16.h>

// Meta3D block: LN1 -> QKV -> MFMA-attn(+rel-pos bias) -> proj(+ls1 resid)
//               LN2 -> FC1+GELU -> FC2(+ls2 resid)
// B=1024 imgs, N=49 tok, C=448. GEMMs are y = x @ W.T (NT), bf16 MFMA 16x16x32.
// R6: (a) GEMM tile 256x128, 8 waves x (64x64 acc=64 AGPR), ring-3 counted
// vmcnt(3), LDS 72KB -> 2 blocks/CU (16 waves). R4 failed because 128-f32 acc
// + 84 VGPR = 212 unified regs -> 2 waves/SIMD; this keeps acc at 64 and forces
// <=128 via __launch_bounds__(512,4). (b) attn: drop sVt staging + barrier,
// V fragments gathered directly from global (predicated); LDS 27.6KB->9KB so
// occupancy goes LDS-capped 5 waves/CU -> VGPR-bound ~12.

#define NTOK 49
#define CDIM 448
#define NHEAD 8
#define DHID 1024
#define HQKV 1536
#define FHID 1792
#define QK_SCALE 0.1767766952966369f
#define INV_SCALE 5.656854249492381f

typedef __attribute__((ext_vector_type(8))) short bf16x8;
typedef __attribute__((ext_vector_type(4))) float f32x4;
typedef unsigned int u32;

__device__ __forceinline__ short f2b(float f) {
    __hip_bfloat16 h = __float2bfloat16(f);
    return *reinterpret_cast<short*>(&h);
}

// async global->LDS, 16B per lane; LDS dest = wave-uniform base + lane*16
__device__ __forceinline__ void gll16(const short* g, short* l) {
    __builtin_amdgcn_global_load_lds(
        (const __attribute__((address_space(1))) u32*)g,
        (__attribute__((address_space(3))) u32*)l, 16, 0, 0);
}

// ---------------- weight fp32 -> bf16 (once per launch) ----------------
__global__ __launch_bounds__(256) void convert_w(
    const float* __restrict__ s0, const float* __restrict__ s1,
    const float* __restrict__ s2, const float* __restrict__ s3,
    short* __restrict__ d0, short* __restrict__ d1,
    short* __restrict__ d2, short* __restrict__ d3)
{
    int i = blockIdx.x * 256 + threadIdx.x;
    if (i < 688128) d0[i] = f2b(s0[i]);        // qkv_w 1536x448
    if (i < 458752) d1[i] = f2b(s1[i]);        // proj_w 448x1024
    if (i < 802816) { d2[i] = f2b(s2[i]);      // fc1_w 1792x448
                      d3[i] = f2b(s3[i]); }    // fc2_w 448x1792
}

// ---------------- expand rel-pos bias to full [8,49,49] fp32 ----------------
__global__ __launch_bounds__(256) void build_bias(
    const float* __restrict__ biases, const int* __restrict__ bidx,
    float* __restrict__ bfull)
{
    int i = blockIdx.x * 256 + threadIdx.x;
    if (i < NHEAD * NTOK * NTOK) {
        int h = i / (NTOK * NTOK), p = i % (NTOK * NTOK);
        bfull[i] = biases[h * NTOK + bidx[p]];
    }
}

// ---------------- LayerNorm: fp32 -> bf16, one wave per 448-row ----------------
__global__ __launch_bounds__(256) void ln_kernel(
    const float* __restrict__ x, short* __restrict__ out,
    const float* __restrict__ g, const float* __restrict__ b)
{
    int row = blockIdx.x * 4 + (threadIdx.x >> 6);
    int lane = threadIdx.x & 63;
    const float* xr = x + (size_t)row * CDIM;
    float v[7];
    float s = 0.f;
#pragma unroll
    for (int i = 0; i < 7; i++) { v[i] = xr[i * 64 + lane]; s += v[i]; }
#pragma unroll
    for (int o = 32; o > 0; o >>= 1) s += __shfl_xor(s, o, 64);
    float mean = s * (1.0f / 448.0f);
    float q = 0.f;
#pragma unroll
    for (int i = 0; i < 7; i++) { float d = v[i] - mean; q += d * d; }
#pragma unroll
    for (int o = 32; o > 0; o >>= 1) q += __shfl_xor(q, o, 64);
    float rstd = rsqrtf(q * (1.0f / 448.0f) + 1e-5f);
    short* orow = out + (size_t)row * CDIM;
#pragma unroll
    for (int i = 0; i < 7; i++) {
        int c = i * 64 + lane;
        orow[c] = f2b((v[i] - mean) * rstd * g[c] + b[c]);
    }
}

// ---------------- bf16 NT GEMM, 256x128 tile, BK=32, 3-deep DMA ring ----------------
// 8 waves (512 thr), wave grid 4(m) x 2(n), 64x64 out per wave (acc 4x4 f32x4).
// Staging per K-step: A 16 panels (16r x 32k, 1KB), B 8 panels; wave w stages
// A-panels {2w,2w+1} + B-panel {w} = 3 gll/wave. Panel layout: DMA dest and
// frag reads are both base + lane*16 (conflict-free).
// Ring (distance 2, 3 buffers): at iter t wait vmcnt(3) (tile t done, tile t+1's
// 3 in flight across the raw s_barrier), then stage tile t+2. Never drain to 0
// in the loop. LDS 72KB -> 2 blocks/CU; launch_bounds(512,4) caps unified
// VGPR+AGPR at 128 (acc=64 AGPR; 32-bit staging offsets keep VGPR low).
// EPI 0: out_bf16 = acc + bias[col]
// EPI 1: out_bf16 = gelu_exact(acc + bias[col])
// EPI 2: out_f32  = resid[row,col] + (acc + bias[col]) * ls[col]
template <int EPI>
__global__ __launch_bounds__(512, 4) void gemm_bt(
    const short* __restrict__ A,     // [M,K] bf16 (rows clamped if M%256)
    const short* __restrict__ W,     // [N,K] bf16 (rows clamped if N%128)
    const float* __restrict__ bias,  // [N]
    const float* __restrict__ ls,    // [N]   (EPI 2)
    const float* __restrict__ resid, // [M,N] (EPI 2)
    float* __restrict__ outF,        // (EPI 2)
    short* __restrict__ outB,        // (EPI 0/1)
    int M, int N, int K)
{
    __shared__ short sA[3][8192];   // 3 x 16KB : 256 rows x 32 k
    __shared__ short sB[3][4096];   // 3 x  8KB : 128 rows x 32 k
    const int tid = threadIdx.x;
    const int lane = tid & 63;
    const int w = tid >> 6;          // 0..7
    const int lr = lane & 15, lq = lane >> 4;
    const int m0 = blockIdx.y * 256;
    const int n0 = blockIdx.x * 128;

    // staging rows (clamped); 32-bit byte offsets from the matrix base
    int rA0 = m0 + (2 * w) * 16 + lr;     rA0 = rA0 < M ? rA0 : M - 1;
    int rA1 = m0 + (2 * w + 1) * 16 + lr; rA1 = rA1 < M ? rA1 : M - 1;
    int rB0 = n0 + w * 16 + lr;           rB0 = rB0 < N ? rB0 : N - 1;
    const u32 kb = (u32)(K + K);          // row stride in bytes
    u32 oA = (u32)rA0 * kb + (u32)(lq * 16);
    u32 oA2 = (u32)rA1 * kb + (u32)(lq * 16);
    u32 oB = (u32)rB0 * kb + (u32)(lq * 16);
    const int dA0 = (2 * w) * 512, dA1 = (2 * w + 1) * 512, dB0 = w * 512;

    const f32x4 fz = {0.f, 0.f, 0.f, 0.f};
    f32x4 acc[4][4];
#pragma unroll
    for (int i = 0; i < 4; i++)
#pragma unroll
        for (int j = 0; j < 4; j++) acc[i][j] = fz;

    const int rdA = (w & 3) * 4096 + lane * 16;   // byte offset inside A buffer
    const int rdB = (w >> 2) * 4096 + lane * 16;  // byte offset inside B buffer

    const int nt = K >> 5;   // 14 / 32 / 56
    // prologue: stage tiles 0 and 1
    gll16((const short*)((const char*)A + oA),  sA[0] + dA0);
    gll16((const short*)((const char*)A + oA2), sA[0] + dA1);
    gll16((const short*)((const char*)W + oB),  sB[0] + dB0);
    oA += 64; oA2 += 64; oB += 64;
    gll16((const short*)((const char*)A + oA),  sA[1] + dA0);
    gll16((const short*)((const char*)A + oA2), sA[1] + dA1);
    gll16((const short*)((const char*)W + oB),  sB[1] + dB0);
    oA += 64; oA2 += 64; oB += 64;

    int bc = 0;   // compute buffer
    int bs = 2;   // stage buffer
    for (int t = 0; t < nt; t++) {
        // tile t's 3 DMAs done; tile t+1's 3 stay in flight across the barrier
        if (t + 1 < nt) asm volatile("s_waitcnt vmcnt(3)" ::: "memory");
        else            asm volatile("s_waitcnt vmcnt(0)" ::: "memory");
        __builtin_amdgcn_s_barrier();
        if (t + 2 < nt) {
            gll16((const short*)((const char*)A + oA),  sA[bs] + dA0);
            gll16((const short*)((const char*)A + oA2), sA[bs] + dA1);
            gll16((const short*)((const char*)W + oB),  sB[bs] + dB0);
            oA += 64; oA2 += 64; oB += 64;
            bs = (bs == 2) ? 0 : bs + 1;
        }
        const char* baseA = (const char*)sA[bc] + rdA;
        const char* baseB = (const char*)sB[bc] + rdB;
        bc = (bc == 2) ? 0 : bc + 1;
        bf16x8 af[4], bfb[4];
#pragma unroll
        for (int i = 0; i < 4; i++) af[i] = *(const bf16x8*)(baseA + i * 1024);
#pragma unroll
        for (int j = 0; j < 4; j++) bfb[j] = *(const bf16x8*)(baseB + j * 1024);
#pragma unroll
        for (int i = 0; i < 4; i++)
#pragma unroll
            for (int j = 0; j < 4; j++)
                acc[i][j] = __builtin_amdgcn_mfma_f32_16x16x32_bf16(
                    af[i], bfb[j], acc[i][j], 0, 0, 0);
    }

    const int wm = (w & 3) * 64, wn = (w >> 2) * 64;
    // C/D layout: col=lane&15, row=(lane>>4)*4+reg  [verified m89/m91]
#pragma unroll
    for (int i = 0; i < 4; i++)
#pragma unroll
        for (int j = 0; j < 4; j++)
#pragma unroll
            for (int r = 0; r < 4; r++) {
                int row = m0 + wm + i * 16 + lq * 4 + r;
                int col = n0 + wn + j * 16 + lr;
                if (row < M && col < N) {
                    float v = acc[i][j][r] + bias[col];
                    if (EPI == 0) {
                        outB[(size_t)row * N + col] = f2b(v);
                    } else if (EPI == 1) {
                        float gl = 0.5f * v * (1.0f + erff(v * 0.7071067811865475f));
                        outB[(size_t)row * N + col] = f2b(gl);
                    } else {
                        outF[(size_t)row * N + col] =
                            resid[(size_t)row * N + col] + v * ls[col];
                    }
                }
            }
}

// ---------------- MFMA attention: 1 wave per (image, head) ----------------
// R6: no V LDS staging, no barrier. V fragments are gathered directly from
// global (predicated tok<49 -> 0; MUST be predicated, OOB rows can be NaN).
// LDS = sP only (9KB) -> occupancy VGPR-bound instead of LDS-capped.
__global__ __launch_bounds__(64) void attn_mfma(
    const short* __restrict__ qkv,    // [R,1536]; per-head 192 = q32|k32|v128
    const float* __restrict__ bfull,  // [8,49,49] fp32
    short* __restrict__ attn_out)     // [R,1024]
{
    __shared__ short sP[64 * 72];     // P bf16, row stride 144B (16B aligned)
    const int head = blockIdx.x;
    const size_t base = (size_t)blockIdx.y * NTOK;
    const int lane = threadIdx.x;
    const int lr = lane & 15, lq = lane >> 4;

    // C-init = bias/SCALE; mask cols>=49 with -1e30 (survives MFMA add + *SCALE)
    f32x4 sc[4][4];
#pragma unroll
    for (int i = 0; i < 4; i++)
#pragma unroll
        for (int j = 0; j < 4; j++)
#pragma unroll
            for (int r = 0; r < 4; r++) {
                int row = i * 16 + lq * 4 + r, col = j * 16 + lr;
                float v;
                if (col >= NTOK)      v = -1e30f;
                else if (row < NTOK)  v = bfull[head * (NTOK * NTOK) + row * NTOK + col] * INV_SCALE;
                else                  v = 0.f;
                sc[i][j][r] = v;
            }

    // Q/K fragments straight from global (k-contiguous 16B; rows clamped)
    bf16x8 qf[4], kf[4];
#pragma unroll
    for (int i = 0; i < 4; i++) {
        int r = i * 16 + lr; r = r < NTOK ? r : NTOK - 1;
        const short* rp = qkv + (base + r) * HQKV + head * 192;
        qf[i] = *(const bf16x8*)(rp + lq * 8);
        kf[i] = *(const bf16x8*)(rp + 32 + lq * 8);
    }
#pragma unroll
    for (int i = 0; i < 4; i++)
#pragma unroll
        for (int j = 0; j < 4; j++)
            sc[i][j] = __builtin_amdgcn_mfma_f32_16x16x32_bf16(
                qf[i], kf[j], sc[i][j], 0, 0, 0);

    // softmax over (j regs x 16 lanes) per output row; P -> sP as bf16
#pragma unroll
    for (int i = 0; i < 4; i++)
#pragma unroll
        for (int r = 0; r < 4; r++) {
            float s0 = sc[i][0][r] * QK_SCALE;
            float s1 = sc[i][1][r] * QK_SCALE;
            float s2 = sc[i][2][r] * QK_SCALE;
            float s3 = sc[i][3][r] * QK_SCALE;
            float m = fmaxf(fmaxf(s0, s1), fmaxf(s2, s3));
#pragma unroll
            for (int o = 1; o < 16; o <<= 1) m = fmaxf(m, __shfl_xor(m, o, 64));
            float e0 = __expf(s0 - m), e1 = __expf(s1 - m);
            float e2 = __expf(s2 - m), e3 = __expf(s3 - m);
            float l = e0 + e1 + e2 + e3;
#pragma unroll
            for (int o = 1; o < 16; o <<= 1) l += __shfl_xor(l, o, 64);
            float inv = 1.0f / l;
            short* pr = &sP[(i * 16 + lq * 4 + r) * 72];
            pr[lr]      = f2b(e0 * inv);
            pr[16 + lr] = f2b(e1 * inv);
            pr[32 + lr] = f2b(e2 * inv);
            pr[48 + lr] = f2b(e3 * inv);
        }
    // single wave: ds_write->ds_read ordered by lgkmcnt, no barrier needed

    // PV: A = P (rows=query, k=token), B rows = V^T[d][tok] gathered from
    // global: element e of frag (j,kk) is V[tok=kk*32+lq*8+e][d] (0 if tok>=49)
    bf16x8 pa[4][2];
#pragma unroll
    for (int i = 0; i < 4; i++)
#pragma unroll
        for (int kk = 0; kk < 2; kk++)
            pa[i][kk] = *(const bf16x8*)&sP[(i * 16 + lr) * 72 + kk * 32 + lq * 8];

#pragma unroll
    for (int half = 0; half < 2; half++) {
        const f32x4 fz = {0.f, 0.f, 0.f, 0.f};
        f32x4 o[4][4];
        bf16x8 pb[4][2];
#pragma unroll
        for (int j = 0; j < 4; j++)
#pragma unroll
            for (int kk = 0; kk < 2; kk++) {
                const int d = half * 64 + j * 16 + lr;
                const short* vcol = qkv + head * 192 + 64 + d;
                bf16x8 tvec;
#pragma unroll
                for (int e = 0; e < 8; e++) {
                    int tok = kk * 32 + lq * 8 + e;
                    tvec[e] = tok < NTOK ? vcol[(base + tok) * HQKV] : (short)0;
                }
                pb[j][kk] = tvec;
            }
#pragma unroll
        for (int i = 0; i < 4; i++)
#pragma unroll
            for (int j = 0; j < 4; j++) {
                o[i][j] = __builtin_amdgcn_mfma_f32_16x16x32_bf16(
                    pa[i][0], pb[j][0], fz, 0, 0, 0);
                o[i][j] = __builtin_amdgcn_mfma_f32_16x16x32_bf16(
                    pa[i][1], pb[j][1], o[i][j], 0, 0, 0);
            }
#pragma unroll
        for (int i = 0; i < 4; i++)
#pragma unroll
            for (int j = 0; j < 4; j++)
#pragma unroll
                for (int r = 0; r < 4; r++) {
                    int row = i * 16 + lq * 4 + r;
                    if (row < NTOK)
                        attn_out[(base + row) * DHID + head * 128 + half * 64 + j * 16 + lr] =
                            f2b(o[i][j][r]);
                }
    }
}

extern "C" void kernel_launch(void* const* d_in, const int* in_sizes, int n_in,
                              void* d_out, int out_size, void* d_ws, size_t ws_size,
                              hipStream_t stream) {
    const float* x      = (const float*)d_in[0];
    const float* qkv_w  = (const float*)d_in[1];
    const float* qkv_b  = (const float*)d_in[2];
    const float* proj_w = (const float*)d_in[3];
    const float* proj_b = (const float*)d_in[4];
    const float* fc1_w  = (const float*)d_in[5];
    const float* fc1_b  = (const float*)d_in[6];
    const float* fc2_w  = (const float*)d_in[7];
    const float* fc2_b  = (const float*)d_in[8];
    const float* n1g    = (const float*)d_in[9];
    const float* n1b    = (const float*)d_in[10];
    const float* n2g    = (const float*)d_in[11];
    const float* n2b    = (const float*)d_in[12];
    const float* ls1    = (const float*)d_in[13];
    const float* ls2    = (const float*)d_in[14];
    const float* biases = (const float*)d_in[15];
    const int*   bidx   = (const int*)d_in[16];
    float* outp = (float*)d_out;

    char* ws = (char*)d_ws;
    short* Wq = (short*)ws; ws += (size_t)688128 * 2;
    short* Wp = (short*)ws; ws += (size_t)458752 * 2;
    short* W1 = (short*)ws; ws += (size_t)802816 * 2;
    short* W2 = (short*)ws; ws += (size_t)802816 * 2;
    float* bfull = (float*)ws; ws += (size_t)NHEAD * NTOK * NTOK * 4;
    const size_t fixed = 5505024 + (size_t)NHEAD * NTOK * NTOK * 4;

    int IC = 1024;
    while (IC > 128) {
        size_t Rr = (size_t)IC * NTOK;
        if (fixed + Rr * 7808ull <= ws_size) break;
        IC >>= 1;
    }
    const size_t R = (size_t)IC * NTOK;
    short* hbuf = (short*)ws; ws += R * CDIM * 2;   // LN out (reused LN2)
    float* x1   = (float*)ws; ws += R * CDIM * 4;   // post-attn residual fp32
    short* qkvb = (short*)ws; ws += R * HQKV * 2;
    short* attb = (short*)ws; ws += R * DHID * 2;
    short* gbuf = qkvb;  // FC1 out [R,1792] overlays qkv+attn (dead by then)

    convert_w<<<3136, 256, 0, stream>>>(qkv_w, proj_w, fc1_w, fc2_w, Wq, Wp, W1, W2);
    build_bias<<<(NHEAD * NTOK * NTOK + 255) / 256, 256, 0, stream>>>(biases, bidx, bfull);

    for (int c0 = 0; c0 < 1024; c0 += IC) {
        const float* xc = x + (size_t)c0 * NTOK * CDIM;
        float* oc = outp + (size_t)c0 * NTOK * CDIM;
        const int Ri = IC * NTOK;
        const int gy = (Ri + 255) / 256;

        ln_kernel<<<Ri / 4, 256, 0, stream>>>(xc, hbuf, n1g, n1b);
        gemm_bt<0><<<dim3(HQKV / 128, gy), 512, 0, stream>>>(
            hbuf, Wq, qkv_b, nullptr, nullptr, nullptr, qkvb, Ri, HQKV, CDIM);
        attn_mfma<<<dim3(NHEAD, IC), 64, 0, stream>>>(qkvb, bfull, attb);
        gemm_bt<2><<<dim3(4, gy), 512, 0, stream>>>(
            attb, Wp, proj_b, ls1, xc, x1, nullptr, Ri, CDIM, DHID);
        ln_kernel<<<Ri / 4, 256, 0, stream>>>(x1, hbuf, n2g, n2b);
        gemm_bt<1><<<dim3(FHID / 128, gy), 512, 0, stream>>>(
            hbuf, W1, fc1_b, nullptr, nullptr, nullptr, gbuf, Ri, FHID, CDIM);
        gemm_bt<2><<<dim3(4, gy), 512, 0, stream>>>(
            gbuf, W2, fc2_b, ls2, x1, oc, nullptr, Ri, CDIM, FHID);
    }
}

// Round 5
// 1116.406 us; speedup vs baseline: 1.4026x; 1.0638x over previous
//
#include <hip/hip_runtime.h>
#include <hip/hip_bf16.h>

// Meta3D block: LN1 -> QKV -> MFMA-attn(+rel-pos bias) -> proj(+ls1 resid)
//               LN2 -> FC1+GELU -> FC2(+ls2 resid)
// B=1024 imgs, N=49 tok, C=448. GEMMs are y = x @ W.T (NT), bf16 MFMA 16x16x32.
// R7: staged-VOLUME attack. GEMM perf tracked staged bytes = 2MNK(1/BM+1/BN)
// across R3-R6 at a stubborn ~6.6 TB/s delivery. 256x256 tile with 16 waves
// (64x64/wave -> 64 AGPR acc, regs <=128, full residency; R4's 256^2 failed on
// 128-AGPR acc = 2 waves/SIMD). Ring: 4 buffers, distance 3, counted vmcnt(4),
// wait-before-barrier (proven R5/R6 invariant). LDS 128KB -> 1 block/CU.
// + m204 bijective XCD swizzle so same-A-panel blocks share an XCD L2.

#define NTOK 49
#define CDIM 448
#define NHEAD 8
#define DHID 1024
#define HQKV 1536
#define FHID 1792
#define QK_SCALE 0.1767766952966369f
#define INV_SCALE 5.656854249492381f

typedef __attribute__((ext_vector_type(8))) short bf16x8;
typedef __attribute__((ext_vector_type(4))) float f32x4;
typedef unsigned int u32;

__device__ __forceinline__ short f2b(float f) {
    __hip_bfloat16 h = __float2bfloat16(f);
    return *reinterpret_cast<short*>(&h);
}

// async global->LDS, 16B per lane; LDS dest = wave-uniform base + lane*16
__device__ __forceinline__ void gll16(const short* g, short* l) {
    __builtin_amdgcn_global_load_lds(
        (const __attribute__((address_space(1))) u32*)g,
        (__attribute__((address_space(3))) u32*)l, 16, 0, 0);
}

// ---------------- weight fp32 -> bf16 (once per launch) ----------------
__global__ __launch_bounds__(256) void convert_w(
    const float* __restrict__ s0, const float* __restrict__ s1,
    const float* __restrict__ s2, const float* __restrict__ s3,
    short* __restrict__ d0, short* __restrict__ d1,
    short* __restrict__ d2, short* __restrict__ d3)
{
    int i = blockIdx.x * 256 + threadIdx.x;
    if (i < 688128) d0[i] = f2b(s0[i]);        // qkv_w 1536x448
    if (i < 458752) d1[i] = f2b(s1[i]);        // proj_w 448x1024
    if (i < 802816) { d2[i] = f2b(s2[i]);      // fc1_w 1792x448
                      d3[i] = f2b(s3[i]); }    // fc2_w 448x1792
}

// ---------------- expand rel-pos bias to full [8,49,49] fp32 ----------------
__global__ __launch_bounds__(256) void build_bias(
    const float* __restrict__ biases, const int* __restrict__ bidx,
    float* __restrict__ bfull)
{
    int i = blockIdx.x * 256 + threadIdx.x;
    if (i < NHEAD * NTOK * NTOK) {
        int h = i / (NTOK * NTOK), p = i % (NTOK * NTOK);
        bfull[i] = biases[h * NTOK + bidx[p]];
    }
}

// ---------------- LayerNorm: fp32 -> bf16, one wave per 448-row ----------------
__global__ __launch_bounds__(256) void ln_kernel(
    const float* __restrict__ x, short* __restrict__ out,
    const float* __restrict__ g, const float* __restrict__ b)
{
    int row = blockIdx.x * 4 + (threadIdx.x >> 6);
    int lane = threadIdx.x & 63;
    const float* xr = x + (size_t)row * CDIM;
    float v[7];
    float s = 0.f;
#pragma unroll
    for (int i = 0; i < 7; i++) { v[i] = xr[i * 64 + lane]; s += v[i]; }
#pragma unroll
    for (int o = 32; o > 0; o >>= 1) s += __shfl_xor(s, o, 64);
    float mean = s * (1.0f / 448.0f);
    float q = 0.f;
#pragma unroll
    for (int i = 0; i < 7; i++) { float d = v[i] - mean; q += d * d; }
#pragma unroll
    for (int o = 32; o > 0; o >>= 1) q += __shfl_xor(q, o, 64);
    float rstd = rsqrtf(q * (1.0f / 448.0f) + 1e-5f);
    short* orow = out + (size_t)row * CDIM;
#pragma unroll
    for (int i = 0; i < 7; i++) {
        int c = i * 64 + lane;
        orow[c] = f2b((v[i] - mean) * rstd * g[c] + b[c]);
    }
}

// ---------------- bf16 NT GEMM, 256x256 tile, BK=32, 4-buf ring distance 3 ----------------
// 16 waves (1024 thr), wave grid 4(m) x 4(n), 64x64 out per wave (acc 4x4 f32x4
// = 64 AGPR). Per K-step each wave stages exactly 2 panels (A panel w, B panel
// w; 16 rows x 32 k, DMA dest = base + lane*16) and reads its 4 A + 4 B frags
// (same conflict-free panel layout as R3-R6).
// Ring: buffers 0..3, prefetch distance 3. At iter t each wave's outstanding
// DMAs are tiles t,t+1,t+2 (6); vmcnt(4) completes tile t, leaves 4 in flight
// across the raw s_barrier; after the barrier stage tile t+3 into buf (t+3)&3
// (its previous occupant t-1 was fully read before this barrier). Wait-before-
// barrier => after barrier ALL waves' tile-t panels are resident.
// EPI 0: out_bf16 = acc + bias[col]
// EPI 1: out_bf16 = gelu_exact(acc + bias[col])
// EPI 2: out_f32  = resid[row,col] + (acc + bias[col]) * ls[col]
template <int EPI>
__global__ __launch_bounds__(1024, 4) void gemm_bt(
    const short* __restrict__ A,     // [M,K] bf16 (rows clamped if M%256)
    const short* __restrict__ W,     // [N,K] bf16 (rows clamped if N%256)
    const float* __restrict__ bias,  // [N]
    const float* __restrict__ ls,    // [N]   (EPI 2)
    const float* __restrict__ resid, // [M,N] (EPI 2)
    float* __restrict__ outF,        // (EPI 2)
    short* __restrict__ outB,        // (EPI 0/1)
    int M, int N, int K)
{
    __shared__ short sA[4][8192];   // 4 x 16KB : 256 rows x 32 k
    __shared__ short sB[4][8192];
    const int tid = threadIdx.x;
    const int lane = tid & 63;
    const int w = tid >> 6;          // 0..15
    const int lr = lane & 15, lq = lane >> 4;

    // m204 bijective XCD swizzle: same-y (same A-panel) blocks contiguous per XCD
    const int gx = gridDim.x;
    const int nwg = gx * gridDim.y;
    const int lin = blockIdx.y * gx + blockIdx.x;
    const int q8 = nwg >> 3, r8 = nwg & 7;
    const int xcd = lin & 7, sub = lin >> 3;
    const int wg = (xcd < r8 ? xcd * (q8 + 1) : r8 * (q8 + 1) + (xcd - r8) * q8) + sub;
    const int m0 = (wg / gx) * 256;
    const int n0 = (wg % gx) * 256;

    // staging: wave w owns A panel w and B panel w (rows clamped)
    int rA = m0 + w * 16 + lr; rA = rA < M ? rA : M - 1;
    int rB = n0 + w * 16 + lr; rB = rB < N ? rB : N - 1;
    const u32 kb = (u32)(K + K);          // row stride in bytes
    u32 oA = (u32)rA * kb + (u32)(lq * 16);
    u32 oB = (u32)rB * kb + (u32)(lq * 16);
    const int dst = w * 512;              // panel offset in shorts

    const f32x4 fz = {0.f, 0.f, 0.f, 0.f};
    f32x4 acc[4][4];
#pragma unroll
    for (int i = 0; i < 4; i++)
#pragma unroll
        for (int j = 0; j < 4; j++) acc[i][j] = fz;

    const int rdA = (w & 3) * 4096 + lane * 16;   // byte offset inside A buffer
    const int rdB = (w >> 2) * 4096 + lane * 16;  // byte offset inside B buffer

    const int nt = K >> 5;   // 14 / 32 / 56
    // prologue: stage tiles 0,1,2 into bufs 0,1,2
#pragma unroll
    for (int p = 0; p < 3; p++) {
        gll16((const short*)((const char*)A + oA), &sA[p][dst]);
        gll16((const short*)((const char*)W + oB), &sB[p][dst]);
        oA += 64; oB += 64;
    }

    int bc = 0;   // compute buffer
    int bs = 3;   // stage buffer
    for (int t = 0; t < nt; t++) {
        const int rem = nt - 1 - t;
        if (rem >= 2)      asm volatile("s_waitcnt vmcnt(4)" ::: "memory");
        else if (rem == 1) asm volatile("s_waitcnt vmcnt(2)" ::: "memory");
        else               asm volatile("s_waitcnt vmcnt(0)" ::: "memory");
        __builtin_amdgcn_s_barrier();
        if (t + 3 < nt) {
            gll16((const short*)((const char*)A + oA), &sA[bs][dst]);
            gll16((const short*)((const char*)W + oB), &sB[bs][dst]);
            oA += 64; oB += 64;
            bs = (bs + 1) & 3;
        }
        const char* baseA = (const char*)sA[bc] + rdA;
        const char* baseB = (const char*)sB[bc] + rdB;
        bc = (bc + 1) & 3;
        bf16x8 af[4], bfb[4];
#pragma unroll
        for (int i = 0; i < 4; i++) af[i] = *(const bf16x8*)(baseA + i * 1024);
#pragma unroll
        for (int j = 0; j < 4; j++) bfb[j] = *(const bf16x8*)(baseB + j * 1024);
#pragma unroll
        for (int i = 0; i < 4; i++)
#pragma unroll
            for (int j = 0; j < 4; j++)
                acc[i][j] = __builtin_amdgcn_mfma_f32_16x16x32_bf16(
                    af[i], bfb[j], acc[i][j], 0, 0, 0);
    }

    const int wm = (w & 3) * 64, wn = (w >> 2) * 64;
    // C/D layout: col=lane&15, row=(lane>>4)*4+reg  [verified m89/m91]
#pragma unroll
    for (int i = 0; i < 4; i++)
#pragma unroll
        for (int j = 0; j < 4; j++)
#pragma unroll
            for (int r = 0; r < 4; r++) {
                int row = m0 + wm + i * 16 + lq * 4 + r;
                int col = n0 + wn + j * 16 + lr;
                if (row < M && col < N) {
                    float v = acc[i][j][r] + bias[col];
                    if (EPI == 0) {
                        outB[(size_t)row * N + col] = f2b(v);
                    } else if (EPI == 1) {
                        float gl = 0.5f * v * (1.0f + erff(v * 0.7071067811865475f));
                        outB[(size_t)row * N + col] = f2b(gl);
                    } else {
                        outF[(size_t)row * N + col] =
                            resid[(size_t)row * N + col] + v * ls[col];
                    }
                }
            }
}

// ---------------- MFMA attention: 1 wave per (image, head) ----------------
// No V LDS staging, no barrier. V fragments gathered directly from global
// (predicated tok<49 -> 0). LDS = sP only (9KB) -> occupancy VGPR-bound.
__global__ __launch_bounds__(64) void attn_mfma(
    const short* __restrict__ qkv,    // [R,1536]; per-head 192 = q32|k32|v128
    const float* __restrict__ bfull,  // [8,49,49] fp32
    short* __restrict__ attn_out)     // [R,1024]
{
    __shared__ short sP[64 * 72];     // P bf16, row stride 144B (16B aligned)
    const int head = blockIdx.x;
    const size_t base = (size_t)blockIdx.y * NTOK;
    const int lane = threadIdx.x;
    const int lr = lane & 15, lq = lane >> 4;

    // C-init = bias/SCALE; mask cols>=49 with -1e30 (survives MFMA add + *SCALE)
    f32x4 sc[4][4];
#pragma unroll
    for (int i = 0; i < 4; i++)
#pragma unroll
        for (int j = 0; j < 4; j++)
#pragma unroll
            for (int r = 0; r < 4; r++) {
                int row = i * 16 + lq * 4 + r, col = j * 16 + lr;
                float v;
                if (col >= NTOK)      v = -1e30f;
                else if (row < NTOK)  v = bfull[head * (NTOK * NTOK) + row * NTOK + col] * INV_SCALE;
                else                  v = 0.f;
                sc[i][j][r] = v;
            }

    // Q/K fragments straight from global (k-contiguous 16B; rows clamped)
    bf16x8 qf[4], kf[4];
#pragma unroll
    for (int i = 0; i < 4; i++) {
        int r = i * 16 + lr; r = r < NTOK ? r : NTOK - 1;
        const short* rp = qkv + (base + r) * HQKV + head * 192;
        qf[i] = *(const bf16x8*)(rp + lq * 8);
        kf[i] = *(const bf16x8*)(rp + 32 + lq * 8);
    }
#pragma unroll
    for (int i = 0; i < 4; i++)
#pragma unroll
        for (int j = 0; j < 4; j++)
            sc[i][j] = __builtin_amdgcn_mfma_f32_16x16x32_bf16(
                qf[i], kf[j], sc[i][j], 0, 0, 0);

    // softmax over (j regs x 16 lanes) per output row; P -> sP as bf16
#pragma unroll
    for (int i = 0; i < 4; i++)
#pragma unroll
        for (int r = 0; r < 4; r++) {
            float s0 = sc[i][0][r] * QK_SCALE;
            float s1 = sc[i][1][r] * QK_SCALE;
            float s2 = sc[i][2][r] * QK_SCALE;
            float s3 = sc[i][3][r] * QK_SCALE;
            float m = fmaxf(fmaxf(s0, s1), fmaxf(s2, s3));
#pragma unroll
            for (int o = 1; o < 16; o <<= 1) m = fmaxf(m, __shfl_xor(m, o, 64));
            float e0 = __expf(s0 - m), e1 = __expf(s1 - m);
            float e2 = __expf(s2 - m), e3 = __expf(s3 - m);
            float l = e0 + e1 + e2 + e3;
#pragma unroll
            for (int o = 1; o < 16; o <<= 1) l += __shfl_xor(l, o, 64);
            float inv = 1.0f / l;
            short* pr = &sP[(i * 16 + lq * 4 + r) * 72];
            pr[lr]      = f2b(e0 * inv);
            pr[16 + lr] = f2b(e1 * inv);
            pr[32 + lr] = f2b(e2 * inv);
            pr[48 + lr] = f2b(e3 * inv);
        }
    // single wave: ds_write->ds_read ordered by lgkmcnt, no barrier needed

    // PV: A = P (rows=query, k=token), B rows = V^T[d][tok] gathered from
    // global: element e of frag (j,kk) is V[tok=kk*32+lq*8+e][d] (0 if tok>=49)
    bf16x8 pa[4][2];
#pragma unroll
    for (int i = 0; i < 4; i++)
#pragma unroll
        for (int kk = 0; kk < 2; kk++)
            pa[i][kk] = *(const bf16x8*)&sP[(i * 16 + lr) * 72 + kk * 32 + lq * 8];

#pragma unroll
    for (int half = 0; half < 2; half++) {
        const f32x4 fz = {0.f, 0.f, 0.f, 0.f};
        f32x4 o[4][4];
        bf16x8 pb[4][2];
#pragma unroll
        for (int j = 0; j < 4; j++)
#pragma unroll
            for (int kk = 0; kk < 2; kk++) {
                const int d = half * 64 + j * 16 + lr;
                const short* vcol = qkv + head * 192 + 64 + d;
                bf16x8 tvec;
#pragma unroll
                for (int e = 0; e < 8; e++) {
                    int tok = kk * 32 + lq * 8 + e;
                    tvec[e] = tok < NTOK ? vcol[(base + tok) * HQKV] : (short)0;
                }
                pb[j][kk] = tvec;
            }
#pragma unroll
        for (int i = 0; i < 4; i++)
#pragma unroll
            for (int j = 0; j < 4; j++) {
                o[i][j] = __builtin_amdgcn_mfma_f32_16x16x32_bf16(
                    pa[i][0], pb[j][0], fz, 0, 0, 0);
                o[i][j] = __builtin_amdgcn_mfma_f32_16x16x32_bf16(
                    pa[i][1], pb[j][1], o[i][j], 0, 0, 0);
            }
#pragma unroll
        for (int i = 0; i < 4; i++)
#pragma unroll
            for (int j = 0; j < 4; j++)
#pragma unroll
                for (int r = 0; r < 4; r++) {
                    int row = i * 16 + lq * 4 + r;
                    if (row < NTOK)
                        attn_out[(base + row) * DHID + head * 128 + half * 64 + j * 16 + lr] =
                            f2b(o[i][j][r]);
                }
    }
}

extern "C" void kernel_launch(void* const* d_in, const int* in_sizes, int n_in,
                              void* d_out, int out_size, void* d_ws, size_t ws_size,
                              hipStream_t stream) {
    const float* x      = (const float*)d_in[0];
    const float* qkv_w  = (const float*)d_in[1];
    const float* qkv_b  = (const float*)d_in[2];
    const float* proj_w = (const float*)d_in[3];
    const float* proj_b = (const float*)d_in[4];
    const float* fc1_w  = (const float*)d_in[5];
    const float* fc1_b  = (const float*)d_in[6];
    const float* fc2_w  = (const float*)d_in[7];
    const float* fc2_b  = (const float*)d_in[8];
    const float* n1g    = (const float*)d_in[9];
    const float* n1b    = (const float*)d_in[10];
    const float* n2g    = (const float*)d_in[11];
    const float* n2b    = (const float*)d_in[12];
    const float* ls1    = (const float*)d_in[13];
    const float* ls2    = (const float*)d_in[14];
    const float* biases = (const float*)d_in[15];
    const int*   bidx   = (const int*)d_in[16];
    float* outp = (float*)d_out;

    char* ws = (char*)d_ws;
    short* Wq = (short*)ws; ws += (size_t)688128 * 2;
    short* Wp = (short*)ws; ws += (size_t)458752 * 2;
    short* W1 = (short*)ws; ws += (size_t)802816 * 2;
    short* W2 = (short*)ws; ws += (size_t)802816 * 2;
    float* bfull = (float*)ws; ws += (size_t)NHEAD * NTOK * NTOK * 4;
    const size_t fixed = 5505024 + (size_t)NHEAD * NTOK * NTOK * 4;

    int IC = 1024;
    while (IC > 128) {
        size_t Rr = (size_t)IC * NTOK;
        if (fixed + Rr * 7808ull <= ws_size) break;
        IC >>= 1;
    }
    const size_t R = (size_t)IC * NTOK;
    short* hbuf = (short*)ws; ws += R * CDIM * 2;   // LN out (reused LN2)
    float* x1   = (float*)ws; ws += R * CDIM * 4;   // post-attn residual fp32
    short* qkvb = (short*)ws; ws += R * HQKV * 2;
    short* attb = (short*)ws; ws += R * DHID * 2;
    short* gbuf = qkvb;  // FC1 out [R,1792] overlays qkv+attn (dead by then)

    convert_w<<<3136, 256, 0, stream>>>(qkv_w, proj_w, fc1_w, fc2_w, Wq, Wp, W1, W2);
    build_bias<<<(NHEAD * NTOK * NTOK + 255) / 256, 256, 0, stream>>>(biases, bidx, bfull);

    for (int c0 = 0; c0 < 1024; c0 += IC) {
        const float* xc = x + (size_t)c0 * NTOK * CDIM;
        float* oc = outp + (size_t)c0 * NTOK * CDIM;
        const int Ri = IC * NTOK;
        const int gy = (Ri + 255) / 256;

        ln_kernel<<<Ri / 4, 256, 0, stream>>>(xc, hbuf, n1g, n1b);
        gemm_bt<0><<<dim3(HQKV / 256, gy), 1024, 0, stream>>>(
            hbuf, Wq, qkv_b, nullptr, nullptr, nullptr, qkvb, Ri, HQKV, CDIM);
        attn_mfma<<<dim3(NHEAD, IC), 64, 0, stream>>>(qkvb, bfull, attb);
        gemm_bt<2><<<dim3(2, gy), 1024, 0, stream>>>(
            attb, Wp, proj_b, ls1, xc, x1, nullptr, Ri, CDIM, DHID);
        ln_kernel<<<Ri / 4, 256, 0, stream>>>(x1, hbuf, n2g, n2b);
        gemm_bt<1><<<dim3(FHID / 256, gy), 1024, 0, stream>>>(
            hbuf, W1, fc1_b, nullptr, nullptr, nullptr, gbuf, Ri, FHID, CDIM);
        gemm_bt<2><<<dim3(2, gy), 1024, 0, stream>>>(
            gbuf, W2, fc2_b, ls2, x1, oc, nullptr, Ri, CDIM, FHID);
    }
}